// Round 1
// baseline (512.368 us; speedup 1.0000x reference)
//
#include <hip/hip_runtime.h>

#define BB 8
#define NN 2048
#define TT 64
#define DD 256
#define KK 128
#define GG 2              // chunks per (b,t)
#define NPT (NN / GG / 256)  // reflected points per thread = 4

// ---------------------------------------------------------------------------
// Kernel 1: for each (b, t) candidate plane, reflect the point cloud and
// count points whose nearest-neighbor distance to the original cloud < 0.05.
// Numerics replicate the JAX/numpy reference exactly (non-FMA, same op order).
// ---------------------------------------------------------------------------
__global__ __launch_bounds__(256) void detect_kernel(
    const float* __restrict__ points,      // [B][N][3]
    const int*   __restrict__ sample_idx,  // [B][T][2]
    int*         __restrict__ counts,      // [B*T] (pre-zeroed)
    float*       __restrict__ planes)      // [B*T][5] = {nx,ny,nz,off,nd}
{
#pragma clang fp contract(off)
    __shared__ float4 spts[NN];   // {x, y, z, ||p||^2}  -> 32 KB
    __shared__ int blk_cnt;

    const int tid   = threadIdx.x;
    const int blk   = blockIdx.x;
    const int bt    = blk / GG;
    const int chunk = blk % GG;
    const int b     = bt / TT;
    const int t     = bt % TT;

    const float* P = points + (size_t)b * NN * 3;

    // stage points + squared norms into LDS
    for (int j = tid; j < NN; j += 256) {
        float x = P[j * 3 + 0];
        float y = P[j * 3 + 1];
        float z = P[j * 3 + 2];
        float s2 = (x * x + y * y) + z * z;   // matches pts_sq op order
        spts[j] = make_float4(x, y, z, s2);
    }
    if (tid == 0) blk_cnt = 0;

    // candidate plane from the sampled pair (uniform across block)
    const int i1 = sample_idx[(b * TT + t) * 2 + 0];
    const int i2 = sample_idx[(b * TT + t) * 2 + 1];
    const float q1x = P[i1 * 3 + 0], q1y = P[i1 * 3 + 1], q1z = P[i1 * 3 + 2];
    const float q2x = P[i2 * 3 + 0], q2y = P[i2 * 3 + 1], q2z = P[i2 * 3 + 2];

    const float dx = q2x - q1x, dy = q2y - q1y, dz = q2z - q1z;
    const float nd  = sqrtf((dx * dx + dy * dy) + dz * dz);
    const float den = nd + 1e-12f;
    const float nx = dx / den, ny = dy / den, nz = dz / den;

    const float e0 = (nx * (q1x + q2x)) * 0.5f;
    const float e1 = (ny * (q1y + q2y)) * 0.5f;
    const float e2 = (nz * (q1z + q2z)) * 0.5f;
    const float off = (e0 + e1) + e2;

    // reflect_points renormalizes again (faithful to reference)
    const float nnorm = sqrtf((nx * nx + ny * ny) + nz * nz);
    const float nden  = nnorm + 1e-12f;
    const float nnx = nx / nden, nny = ny / nden, nnz = nz / nden;

    __syncthreads();

    // per-thread reflected points (register-blocked)
    float rx[NPT], ry[NPT], rz[NPT], rsq[NPT], mind[NPT];
    const int base = chunk * (NN / GG);
#pragma unroll
    for (int k = 0; k < NPT; ++k) {
        const int n = base + tid + k * 256;
        const float4 p = spts[n];
        const float sd = ((p.x * nnx + p.y * nny) + p.z * nnz) - off;
        const float s  = 2.0f * sd;
        rx[k] = p.x - s * nnx;
        ry[k] = p.y - s * nny;
        rz[k] = p.z - s * nnz;
        rsq[k] = (rx[k] * rx[k] + ry[k] * ry[k]) + rz[k] * rz[k];
        mind[k] = 3.4e38f;
    }

    // brute-force nearest neighbor: one broadcast ds_read_b128 per m,
    // 4 x 9 non-FMA VALU ops amortize it (VALU-bound)
#pragma unroll 4
    for (int m = 0; m < NN; ++m) {
        const float4 p = spts[m];
#pragma unroll
        for (int k = 0; k < NPT; ++k) {
            const float cross = (rx[k] * p.x + ry[k] * p.y) + rz[k] * p.z;
            const float t1 = rsq[k] + p.w;          // r_sq + pts_sq
            const float d2 = t1 - 2.0f * cross;     // - 2*cross (no FMA)
            mind[k] = fminf(mind[k], d2);
        }
    }

    int cnt = 0;
#pragma unroll
    for (int k = 0; k < NPT; ++k) {
        const float md = sqrtf(fmaxf(mind[k], 0.0f));
        cnt += (md < 0.05f) ? 1 : 0;
    }
    atomicAdd(&blk_cnt, cnt);
    __syncthreads();

    if (tid == 0) {
        atomicAdd(&counts[bt], blk_cnt);
        if (chunk == 0) {
            planes[bt * 5 + 0] = nx;
            planes[bt * 5 + 1] = ny;
            planes[bt * 5 + 2] = nz;
            planes[bt * 5 + 3] = off;
            planes[bt * 5 + 4] = nd;
        }
    }
}

// ---------------------------------------------------------------------------
// Kernel 2: per-batch sequential argmax (first-wins ties, frac > best),
// centroid, sym features, GEMV z_aug @ W.T + b, and small outputs.
// ---------------------------------------------------------------------------
__global__ __launch_bounds__(256) void finalize_kernel(
    const float* __restrict__ points,   // [B][N][3]
    const float* __restrict__ z_enc,    // [B][D]
    const float* __restrict__ Wm,       // [D][D+4]
    const float* __restrict__ bias,     // [D]
    const int*   __restrict__ counts,   // [B*T]
    const float* __restrict__ planes,   // [B*T][5]
    float*       __restrict__ out)      // concat outputs
{
    const int b   = blockIdx.x;
    const int tid = threadIdx.x;

    __shared__ float zaug[DD + 4];
    __shared__ float red[3][256];

    // centroid partial sums
    const float* P = points + (size_t)b * NN * 3;
    float sx = 0.f, sy = 0.f, sz = 0.f;
    for (int j = tid; j < NN; j += 256) {
        sx += P[j * 3 + 0];
        sy += P[j * 3 + 1];
        sz += P[j * 3 + 2];
    }
    red[0][tid] = sx; red[1][tid] = sy; red[2][tid] = sz;

    // stage z_enc
    zaug[tid] = z_enc[b * DD + tid];
    __syncthreads();

    for (int s = 128; s > 0; s >>= 1) {
        if (tid < s) {
            red[0][tid] += red[0][tid + s];
            red[1][tid] += red[1][tid + s];
            red[2][tid] += red[2][tid + s];
        }
        __syncthreads();
    }

    if (tid == 0) {
        const float cx = red[0][0] / (float)NN;
        const float cy = red[1][0] / (float)NN;
        const float cz = red[2][0] / (float)NN;

        // sequential scan: update only on strictly-greater frac (first wins)
        float bn0 = 0.f, bn1 = 1.f, bn2 = 0.f, bo = 0.f, bc = 0.f;
        for (int t = 0; t < TT; ++t) {
            const int bt = b * TT + t;
            const float ndv = planes[bt * 5 + 4];
            const float frac = (ndv < 1e-8f) ? -1.0f
                               : (float)counts[bt] * (1.0f / 2048.0f);
            if (frac > bc) {
                bn0 = planes[bt * 5 + 0];
                bn1 = planes[bt * 5 + 1];
                bn2 = planes[bt * 5 + 2];
                bo  = planes[bt * 5 + 3];
                bc  = frac;
            }
        }
        const float sd = ((bn0 * cx + bn1 * cy) + bn2 * cz) - bo;
        zaug[DD + 0] = bn0;
        zaug[DD + 1] = bn1;
        zaug[DD + 2] = bn2;
        zaug[DD + 3] = sd;

        float* normals = out + (BB * DD + BB * KK * DD);
        normals[b * 3 + 0] = bn0;
        normals[b * 3 + 1] = bn1;
        normals[b * 3 + 2] = bn2;
        float* offs = normals + BB * 3;
        offs[b] = bo;
        float* conf = offs + BB;
        conf[b] = bc;
    }
    __syncthreads();

    // GEMV: out[b][d] = sum_j zaug[j] * W[d][j] + bias[d]
    const float* wrow = Wm + (size_t)tid * (DD + 4);
    float acc = bias[tid];
    for (int j = 0; j < DD + 4; ++j) acc += zaug[j] * wrow[j];
    out[b * DD + tid] = acc;
}

extern "C" void kernel_launch(void* const* d_in, const int* in_sizes, int n_in,
                              void* d_out, int out_size, void* d_ws, size_t ws_size,
                              hipStream_t stream) {
    const float* points     = (const float*)d_in[0];
    const float* z_enc      = (const float*)d_in[1];
    const float* z_local    = (const float*)d_in[2];
    // d_in[3] = proxy_coords (unused by reference outputs)
    const int*   sample_idx = (const int*)d_in[4];
    const float* Wm         = (const float*)d_in[5];
    const float* bias       = (const float*)d_in[6];
    float* out = (float*)d_out;

    int*   counts = (int*)d_ws;
    float* planes = (float*)((char*)d_ws + BB * TT * sizeof(int));

    // zero the per-(b,t) match counters (d_ws is poisoned)
    hipMemsetAsync(counts, 0, BB * TT * sizeof(int), stream);

    // z_local passthrough: out[B*D : B*D + B*K*D]
    hipMemcpyAsync(out + BB * DD, z_local,
                   (size_t)BB * KK * DD * sizeof(float),
                   hipMemcpyDeviceToDevice, stream);

    detect_kernel<<<BB * TT * GG, 256, 0, stream>>>(points, sample_idx, counts, planes);
    finalize_kernel<<<BB, 256, 0, stream>>>(points, z_enc, Wm, bias, counts, planes, out);
}

// Round 2
// 369.536 us; speedup vs baseline: 1.3865x; 1.3865x over previous
//
#include <hip/hip_runtime.h>

#define BB 8
#define NN 2048
#define TT 64
#define DD 256
#define KK 128
#define GG 2               // chunks per (b,t)
#define THREADS 512
#define NPT (NN / GG / THREADS)  // reflected points per thread = 2

// ---------------------------------------------------------------------------
// Kernel 1: for each (b, t) candidate plane, reflect the point cloud and
// count points whose nearest-neighbor distance to the original cloud < 0.05.
// Numerics replicate the reference bit-exactly:
//  - expansion form d2 = (rsq + psq) - 2*cross, non-FMA, left-assoc adds
//  - 2*cross realized as dot(2r, p) (exact power-of-2 scaling commutes
//    with rounding), saving one multiply per pair
//  - sqrt(max(d2,0)) < 0.05f  <=>  d2 < 0.0025f  (exact boundary analysis)
// ---------------------------------------------------------------------------
__global__ __launch_bounds__(THREADS) void detect_kernel(
    const float* __restrict__ points,      // [B][N][3]
    const int*   __restrict__ sample_idx,  // [B][T][2]
    int*         __restrict__ counts,      // [B*T] (pre-zeroed)
    float*       __restrict__ planes)      // [B*T][5] = {nx,ny,nz,off,nd}
{
#pragma clang fp contract(off)
    __shared__ float4 spts[NN];   // {x, y, z, ||p||^2} -> exactly 32768 B

    const int tid   = threadIdx.x;
    const int blk   = blockIdx.x;
    const int bt    = blk / GG;
    const int chunk = blk % GG;
    const int b     = bt / TT;
    const int t     = bt % TT;

    const float* P = points + (size_t)b * NN * 3;

    // stage points + squared norms into LDS
    for (int j = tid; j < NN; j += THREADS) {
        float x = P[j * 3 + 0];
        float y = P[j * 3 + 1];
        float z = P[j * 3 + 2];
        float s2 = (x * x + y * y) + z * z;   // matches pts_sq op order
        spts[j] = make_float4(x, y, z, s2);
    }

    // candidate plane from the sampled pair (uniform across block)
    const int i1 = sample_idx[(b * TT + t) * 2 + 0];
    const int i2 = sample_idx[(b * TT + t) * 2 + 1];
    const float q1x = P[i1 * 3 + 0], q1y = P[i1 * 3 + 1], q1z = P[i1 * 3 + 2];
    const float q2x = P[i2 * 3 + 0], q2y = P[i2 * 3 + 1], q2z = P[i2 * 3 + 2];

    const float dx = q2x - q1x, dy = q2y - q1y, dz = q2z - q1z;
    const float nd  = sqrtf((dx * dx + dy * dy) + dz * dz);
    const float den = nd + 1e-12f;
    const float nx = dx / den, ny = dy / den, nz = dz / den;

    const float e0 = (nx * (q1x + q2x)) * 0.5f;
    const float e1 = (ny * (q1y + q2y)) * 0.5f;
    const float e2 = (nz * (q1z + q2z)) * 0.5f;
    const float off = (e0 + e1) + e2;

    // reflect_points renormalizes again (faithful to reference)
    const float nnorm = sqrtf((nx * nx + ny * ny) + nz * nz);
    const float nden  = nnorm + 1e-12f;
    const float nnx = nx / nden, nny = ny / nden, nnz = nz / nden;

    __syncthreads();

    // two reflected points per thread (register-resident)
    const int n0 = chunk * (NN / GG) + tid;
    const int n1 = n0 + THREADS;

    float r2x0, r2y0, r2z0, rsq0, r2x1, r2y1, r2z1, rsq1;
    {
        const float4 p0 = spts[n0];
        const float sd = ((p0.x * nnx + p0.y * nny) + p0.z * nnz) - off;
        const float s  = 2.0f * sd;
        const float rx = p0.x - s * nnx;
        const float ry = p0.y - s * nny;
        const float rz = p0.z - s * nnz;
        rsq0 = (rx * rx + ry * ry) + rz * rz;
        r2x0 = rx + rx; r2y0 = ry + ry; r2z0 = rz + rz;  // exact *2
    }
    {
        const float4 p1 = spts[n1];
        const float sd = ((p1.x * nnx + p1.y * nny) + p1.z * nnz) - off;
        const float s  = 2.0f * sd;
        const float rx = p1.x - s * nnx;
        const float ry = p1.y - s * nny;
        const float rz = p1.z - s * nnz;
        rsq1 = (rx * rx + ry * ry) + rz * rz;
        r2x1 = rx + rx; r2y1 = ry + ry; r2z1 = rz + rz;
    }

    // brute-force NN over all m: 8 non-FMA VALU ops per (m,k) pair,
    // register double-buffer keeps ds_read latency off the critical path
    float md0 = 3.4e38f, md1 = 3.4e38f;
    float4 p = spts[0];
#pragma unroll 8
    for (int m = 0; m < NN - 1; ++m) {
        const float4 pn = spts[m + 1];
        {
            const float c0 = (r2x0 * p.x + r2y0 * p.y) + r2z0 * p.z; // = 2*cross
            const float t0 = rsq0 + p.w;
            md0 = fminf(md0, t0 - c0);
            const float c1 = (r2x1 * p.x + r2y1 * p.y) + r2z1 * p.z;
            const float t1 = rsq1 + p.w;
            md1 = fminf(md1, t1 - c1);
        }
        p = pn;
    }
    {
        const float c0 = (r2x0 * p.x + r2y0 * p.y) + r2z0 * p.z;
        const float t0 = rsq0 + p.w;
        md0 = fminf(md0, t0 - c0);
        const float c1 = (r2x1 * p.x + r2y1 * p.y) + r2z1 * p.z;
        const float t1 = rsq1 + p.w;
        md1 = fminf(md1, t1 - c1);
    }

    // matched <=> min d2 < 0.0025f (exactly equivalent to sqrt-form)
    const unsigned long long b0 = __ballot(md0 < 0.0025f);
    const unsigned long long b1 = __ballot(md1 < 0.0025f);
    if ((tid & 63) == 0) {
        atomicAdd(&counts[bt], __popcll(b0) + __popcll(b1));
    }

    if (tid == 0 && chunk == 0) {
        planes[bt * 5 + 0] = nx;
        planes[bt * 5 + 1] = ny;
        planes[bt * 5 + 2] = nz;
        planes[bt * 5 + 3] = off;
        planes[bt * 5 + 4] = nd;
    }
}

// ---------------------------------------------------------------------------
// Kernel 2: per-batch sequential argmax (first-wins ties, frac > best),
// centroid, sym features, GEMV z_aug @ W.T + b, and small outputs.
// ---------------------------------------------------------------------------
__global__ __launch_bounds__(256) void finalize_kernel(
    const float* __restrict__ points,   // [B][N][3]
    const float* __restrict__ z_enc,    // [B][D]
    const float* __restrict__ Wm,       // [D][D+4]
    const float* __restrict__ bias,     // [D]
    const int*   __restrict__ counts,   // [B*T]
    const float* __restrict__ planes,   // [B*T][5]
    float*       __restrict__ out)      // concat outputs
{
    const int b   = blockIdx.x;
    const int tid = threadIdx.x;

    __shared__ float zaug[DD + 4];
    __shared__ float red[3][256];

    // centroid partial sums
    const float* P = points + (size_t)b * NN * 3;
    float sx = 0.f, sy = 0.f, sz = 0.f;
    for (int j = tid; j < NN; j += 256) {
        sx += P[j * 3 + 0];
        sy += P[j * 3 + 1];
        sz += P[j * 3 + 2];
    }
    red[0][tid] = sx; red[1][tid] = sy; red[2][tid] = sz;

    // stage z_enc
    zaug[tid] = z_enc[b * DD + tid];
    __syncthreads();

    for (int s = 128; s > 0; s >>= 1) {
        if (tid < s) {
            red[0][tid] += red[0][tid + s];
            red[1][tid] += red[1][tid + s];
            red[2][tid] += red[2][tid + s];
        }
        __syncthreads();
    }

    if (tid == 0) {
        const float cx = red[0][0] / (float)NN;
        const float cy = red[1][0] / (float)NN;
        const float cz = red[2][0] / (float)NN;

        // sequential scan: update only on strictly-greater frac (first wins)
        float bn0 = 0.f, bn1 = 1.f, bn2 = 0.f, bo = 0.f, bc = 0.f;
        for (int t = 0; t < TT; ++t) {
            const int bt = b * TT + t;
            const float ndv = planes[bt * 5 + 4];
            const float frac = (ndv < 1e-8f) ? -1.0f
                               : (float)counts[bt] * (1.0f / 2048.0f);
            if (frac > bc) {
                bn0 = planes[bt * 5 + 0];
                bn1 = planes[bt * 5 + 1];
                bn2 = planes[bt * 5 + 2];
                bo  = planes[bt * 5 + 3];
                bc  = frac;
            }
        }
        const float sd = ((bn0 * cx + bn1 * cy) + bn2 * cz) - bo;
        zaug[DD + 0] = bn0;
        zaug[DD + 1] = bn1;
        zaug[DD + 2] = bn2;
        zaug[DD + 3] = sd;

        float* normals = out + (BB * DD + BB * KK * DD);
        normals[b * 3 + 0] = bn0;
        normals[b * 3 + 1] = bn1;
        normals[b * 3 + 2] = bn2;
        float* offs = normals + BB * 3;
        offs[b] = bo;
        float* conf = offs + BB;
        conf[b] = bc;
    }
    __syncthreads();

    // GEMV: out[b][d] = sum_j zaug[j] * W[d][j] + bias[d]
    const float* wrow = Wm + (size_t)tid * (DD + 4);
    float acc = bias[tid];
    for (int j = 0; j < DD + 4; ++j) acc += zaug[j] * wrow[j];
    out[b * DD + tid] = acc;
}

extern "C" void kernel_launch(void* const* d_in, const int* in_sizes, int n_in,
                              void* d_out, int out_size, void* d_ws, size_t ws_size,
                              hipStream_t stream) {
    const float* points     = (const float*)d_in[0];
    const float* z_enc      = (const float*)d_in[1];
    const float* z_local    = (const float*)d_in[2];
    // d_in[3] = proxy_coords (unused by reference outputs)
    const int*   sample_idx = (const int*)d_in[4];
    const float* Wm         = (const float*)d_in[5];
    const float* bias       = (const float*)d_in[6];
    float* out = (float*)d_out;

    int*   counts = (int*)d_ws;
    float* planes = (float*)((char*)d_ws + BB * TT * sizeof(int));

    // zero the per-(b,t) match counters (d_ws is poisoned)
    hipMemsetAsync(counts, 0, BB * TT * sizeof(int), stream);

    // z_local passthrough: out[B*D : B*D + B*K*D]
    hipMemcpyAsync(out + BB * DD, z_local,
                   (size_t)BB * KK * DD * sizeof(float),
                   hipMemcpyDeviceToDevice, stream);

    detect_kernel<<<BB * TT * GG, THREADS, 0, stream>>>(points, sample_idx, counts, planes);
    finalize_kernel<<<BB, 256, 0, stream>>>(points, z_enc, Wm, bias, counts, planes, out);
}

// Round 3
// 62.987 us; speedup vs baseline: 8.1345x; 5.8668x over previous
//
#include <hip/hip_runtime.h>

#define BB 8
#define NN 2048
#define TT 64
#define DD 256
#define KK 128

// ---- spatial grid ----
#define GSZ 32
#define NC (GSZ * GSZ * GSZ)
#define DTHR 0.053f     // conservative per-dim candidate radius (covers fp error)
#define D2THR 0.0025f   // sqrt(max(d2,0)) < 0.05  <=>  d2 < 0.0025 (exact)

// ---- workspace layout (bytes) ----
#define WS_COUNTS 0
#define WS_PLANES 2048
#define WS_GRIDP  12288
#define WS_HEAD   12672
#define WS_NXT    (12672 + BB * NC * 4)
#define WS_NEEDED (WS_NXT + BB * NN * 4)

// fallback (round-2 brute force) config
#define GG 2
#define FTHREADS 512

// ---------------------------------------------------------------------------
// per-batch bounding box -> grid params {org[3], h[3], inv_h[3]}
// h = max(extent/31.9, 0.06) guarantees every point maps to cell [0,31]
// and h > DTHR so +-1 cells cover the candidate radius.
// ---------------------------------------------------------------------------
__global__ __launch_bounds__(256) void bbox_kernel(
    const float* __restrict__ points, float* __restrict__ gridp)
{
#pragma clang fp contract(off)
    const int b = blockIdx.x, tid = threadIdx.x;
    const float* P = points + (size_t)b * NN * 3;
    float mn[3] = {3.4e38f, 3.4e38f, 3.4e38f};
    float mx[3] = {-3.4e38f, -3.4e38f, -3.4e38f};
    for (int j = tid; j < NN; j += 256)
        for (int d = 0; d < 3; ++d) {
            float v = P[j * 3 + d];
            mn[d] = fminf(mn[d], v);
            mx[d] = fmaxf(mx[d], v);
        }
    __shared__ float smn[3][256], smx[3][256];
    for (int d = 0; d < 3; ++d) { smn[d][tid] = mn[d]; smx[d][tid] = mx[d]; }
    __syncthreads();
    for (int s = 128; s > 0; s >>= 1) {
        if (tid < s)
            for (int d = 0; d < 3; ++d) {
                smn[d][tid] = fminf(smn[d][tid], smn[d][tid + s]);
                smx[d][tid] = fmaxf(smx[d][tid], smx[d][tid + s]);
            }
        __syncthreads();
    }
    if (tid == 0) {
        float* g = gridp + b * 12;
        for (int d = 0; d < 3; ++d) {
            float org = smn[d][0] - 1e-3f;
            float h = fmaxf((smx[d][0] - org) * (1.0f / 31.9f), 0.06f);
            g[d] = org; g[3 + d] = h; g[6 + d] = 1.0f / h;
        }
    }
}

// ---------------------------------------------------------------------------
// build per-batch linked-list grid: head[b][cell] -> point idx chain via nxt
// ---------------------------------------------------------------------------
__global__ __launch_bounds__(256) void build_kernel(
    const float* __restrict__ points, const float* __restrict__ gridp,
    int* __restrict__ head, int* __restrict__ nxt)
{
#pragma clang fp contract(off)
    const int b = blockIdx.x, tid = threadIdx.x;
    const float* P = points + (size_t)b * NN * 3;
    const float* g = gridp + b * 12;
    for (int j = tid; j < NN; j += 256) {
        int c[3];
        for (int d = 0; d < 3; ++d) {
            int ci = (int)floorf((P[j * 3 + d] - g[d]) * g[6 + d]);
            c[d] = min(GSZ - 1, max(0, ci));
        }
        const int cell = (c[2] * GSZ + c[1]) * GSZ + c[0];
        nxt[b * NN + j] = atomicExch(&head[b * NC + cell], j);
    }
}

// ---------------------------------------------------------------------------
// one block per (b,t): reflect 2048 points, count grid-pruned exact matches.
// Exact d2 = (rsq + pts_sq) - dot(2r, p), non-FMA, bit-identical to reference.
// ---------------------------------------------------------------------------
__global__ __launch_bounds__(512) void detect_grid_kernel(
    const float* __restrict__ points, const int* __restrict__ sample_idx,
    const float* __restrict__ gridp, const int* __restrict__ head,
    const int* __restrict__ nxt, int* __restrict__ counts,
    float* __restrict__ planes)
{
#pragma clang fp contract(off)
    __shared__ float4 spts[NN];   // {x,y,z,||p||^2}
    __shared__ int snext[NN];
    __shared__ int blk_cnt;

    const int tid = threadIdx.x;
    const int bt  = blockIdx.x;
    const int b   = bt / TT;

    const float* P = points + (size_t)b * NN * 3;
    for (int j = tid; j < NN; j += 512) {
        float x = P[j * 3 + 0], y = P[j * 3 + 1], z = P[j * 3 + 2];
        spts[j]  = make_float4(x, y, z, (x * x + y * y) + z * z);
        snext[j] = nxt[b * NN + j];
    }
    if (tid == 0) blk_cnt = 0;

    // candidate plane (uniform across block) — exact reference ops
    const int i1 = sample_idx[bt * 2 + 0];
    const int i2 = sample_idx[bt * 2 + 1];
    const float q1x = P[i1 * 3 + 0], q1y = P[i1 * 3 + 1], q1z = P[i1 * 3 + 2];
    const float q2x = P[i2 * 3 + 0], q2y = P[i2 * 3 + 1], q2z = P[i2 * 3 + 2];
    const float dx0 = q2x - q1x, dy0 = q2y - q1y, dz0 = q2z - q1z;
    const float nd  = sqrtf((dx0 * dx0 + dy0 * dy0) + dz0 * dz0);
    const float den = nd + 1e-12f;
    const float nx = dx0 / den, ny = dy0 / den, nz = dz0 / den;
    const float e0 = (nx * (q1x + q2x)) * 0.5f;
    const float e1 = (ny * (q1y + q2y)) * 0.5f;
    const float e2 = (nz * (q1z + q2z)) * 0.5f;
    const float off = (e0 + e1) + e2;
    const float nnorm = sqrtf((nx * nx + ny * ny) + nz * nz);
    const float nden  = nnorm + 1e-12f;
    const float nnx = nx / nden, nny = ny / nden, nnz = nz / nden;

    const float* g = gridp + b * 12;
    const float ogx = g[0], ogy = g[1], ogz = g[2];
    const float hx = g[3], hy = g[4], hz = g[5];
    const float ivx = g[6], ivy = g[7], ivz = g[8];
    const int* headb = head + b * NC;

    __syncthreads();

    int cnt = 0;
    for (int q = 0; q < NN / 512; ++q) {
        const int n = tid + q * 512;
        const float4 p = spts[n];
        const float sd = ((p.x * nnx + p.y * nny) + p.z * nnz) - off;
        const float s  = 2.0f * sd;
        const float rx = p.x - s * nnx;
        const float ry = p.y - s * nny;
        const float rz = p.z - s * nnz;
        const float rsq = (rx * rx + ry * ry) + rz * rz;
        const float r2x = rx + rx, r2y = ry + ry, r2z = rz + rz; // exact *2

        // locate cell (unclamped base + per-dim +-1 range, clamp by skip)
        const float tx = rx - ogx; const float cfx = floorf(tx * ivx);
        const float ty = ry - ogy; const float cfy = floorf(ty * ivy);
        const float tz = rz - ogz; const float cfz = floorf(tz * ivz);
        const int cxi = (int)cfx, cyi = (int)cfy, czi = (int)cfz;
        const float fx = tx - cfx * hx;
        const float fy = ty - cfy * hy;
        const float fz = tz - cfz * hz;
        const int lx = (fx < DTHR) ? -1 : 0, ux = (fx > hx - DTHR) ? 1 : 0;
        const int ly = (fy < DTHR) ? -1 : 0, uy = (fy > hy - DTHR) ? 1 : 0;
        const int lz = (fz < DTHR) ? -1 : 0, uz = (fz > hz - DTHR) ? 1 : 0;

        int matched = 0;
        for (int dz = lz; dz <= uz; ++dz) {
            const int cz = czi + dz; if ((unsigned)cz >= GSZ) continue;
            for (int dy = ly; dy <= uy; ++dy) {
                const int cy = cyi + dy; if ((unsigned)cy >= GSZ) continue;
                for (int dxi = lx; dxi <= ux; ++dxi) {
                    const int cx = cxi + dxi; if ((unsigned)cx >= GSZ) continue;
                    int j = headb[(cz * GSZ + cy) * GSZ + cx];
                    while (j >= 0) {
                        const float4 pm = spts[j];
                        const float c2 = (r2x * pm.x + r2y * pm.y) + r2z * pm.z;
                        const float t1 = rsq + pm.w;
                        matched |= ((t1 - c2) < D2THR) ? 1 : 0;
                        j = snext[j];
                    }
                }
            }
        }
        cnt += matched;
    }

    for (int o = 32; o > 0; o >>= 1) cnt += __shfl_down(cnt, o);
    if ((tid & 63) == 0) atomicAdd(&blk_cnt, cnt);
    __syncthreads();

    if (tid == 0) {
        counts[bt] = blk_cnt;
        planes[bt * 5 + 0] = nx;
        planes[bt * 5 + 1] = ny;
        planes[bt * 5 + 2] = nz;
        planes[bt * 5 + 3] = off;
        planes[bt * 5 + 4] = nd;
    }
}

// ---------------------------------------------------------------------------
// Fallback brute-force detect (round-2 kernel) if ws_size is too small.
// ---------------------------------------------------------------------------
__global__ __launch_bounds__(FTHREADS) void detect_fallback_kernel(
    const float* __restrict__ points, const int* __restrict__ sample_idx,
    int* __restrict__ counts, float* __restrict__ planes)
{
#pragma clang fp contract(off)
    __shared__ float4 spts[NN];
    const int tid = threadIdx.x;
    const int blk = blockIdx.x;
    const int bt = blk / GG, chunk = blk % GG, b = bt / TT;
    const float* P = points + (size_t)b * NN * 3;
    for (int j = tid; j < NN; j += FTHREADS) {
        float x = P[j*3], y = P[j*3+1], z = P[j*3+2];
        spts[j] = make_float4(x, y, z, (x*x + y*y) + z*z);
    }
    const int i1 = sample_idx[bt * 2 + 0];
    const int i2 = sample_idx[bt * 2 + 1];
    const float q1x = P[i1*3], q1y = P[i1*3+1], q1z = P[i1*3+2];
    const float q2x = P[i2*3], q2y = P[i2*3+1], q2z = P[i2*3+2];
    const float dx = q2x - q1x, dy = q2y - q1y, dz = q2z - q1z;
    const float nd  = sqrtf((dx*dx + dy*dy) + dz*dz);
    const float den = nd + 1e-12f;
    const float nx = dx/den, ny = dy/den, nz = dz/den;
    const float e0 = (nx*(q1x+q2x))*0.5f, e1 = (ny*(q1y+q2y))*0.5f, e2 = (nz*(q1z+q2z))*0.5f;
    const float off = (e0 + e1) + e2;
    const float nnorm = sqrtf((nx*nx + ny*ny) + nz*nz);
    const float nden = nnorm + 1e-12f;
    const float nnx = nx/nden, nny = ny/nden, nnz = nz/nden;
    __syncthreads();
    const int n0 = chunk * (NN / GG) + tid;
    const int n1 = n0 + FTHREADS;
    float r2x0, r2y0, r2z0, rsq0, r2x1, r2y1, r2z1, rsq1;
    {
        const float4 p0 = spts[n0];
        const float sd = ((p0.x*nnx + p0.y*nny) + p0.z*nnz) - off;
        const float s = 2.0f*sd;
        const float rx = p0.x - s*nnx, ry = p0.y - s*nny, rz = p0.z - s*nnz;
        rsq0 = (rx*rx + ry*ry) + rz*rz;
        r2x0 = rx+rx; r2y0 = ry+ry; r2z0 = rz+rz;
    }
    {
        const float4 p1 = spts[n1];
        const float sd = ((p1.x*nnx + p1.y*nny) + p1.z*nnz) - off;
        const float s = 2.0f*sd;
        const float rx = p1.x - s*nnx, ry = p1.y - s*nny, rz = p1.z - s*nnz;
        rsq1 = (rx*rx + ry*ry) + rz*rz;
        r2x1 = rx+rx; r2y1 = ry+ry; r2z1 = rz+rz;
    }
    float md0 = 3.4e38f, md1 = 3.4e38f;
    float4 p = spts[0];
#pragma unroll 8
    for (int m = 0; m < NN - 1; ++m) {
        const float4 pn = spts[m + 1];
        const float c0 = (r2x0*p.x + r2y0*p.y) + r2z0*p.z;
        md0 = fminf(md0, (rsq0 + p.w) - c0);
        const float c1 = (r2x1*p.x + r2y1*p.y) + r2z1*p.z;
        md1 = fminf(md1, (rsq1 + p.w) - c1);
        p = pn;
    }
    {
        const float c0 = (r2x0*p.x + r2y0*p.y) + r2z0*p.z;
        md0 = fminf(md0, (rsq0 + p.w) - c0);
        const float c1 = (r2x1*p.x + r2y1*p.y) + r2z1*p.z;
        md1 = fminf(md1, (rsq1 + p.w) - c1);
    }
    const unsigned long long b0 = __ballot(md0 < D2THR);
    const unsigned long long b1 = __ballot(md1 < D2THR);
    if ((tid & 63) == 0) atomicAdd(&counts[bt], __popcll(b0) + __popcll(b1));
    if (tid == 0 && chunk == 0) {
        planes[bt*5+0] = nx; planes[bt*5+1] = ny; planes[bt*5+2] = nz;
        planes[bt*5+3] = off; planes[bt*5+4] = nd;
    }
}

// ---------------------------------------------------------------------------
// Kernel: per-batch argmax (first-wins), centroid, GEMV, small outputs.
// ---------------------------------------------------------------------------
__global__ __launch_bounds__(256) void finalize_kernel(
    const float* __restrict__ points, const float* __restrict__ z_enc,
    const float* __restrict__ Wm, const float* __restrict__ bias,
    const int* __restrict__ counts, const float* __restrict__ planes,
    float* __restrict__ out)
{
    const int b = blockIdx.x, tid = threadIdx.x;
    __shared__ float zaug[DD + 4];
    __shared__ float red[3][256];

    const float* P = points + (size_t)b * NN * 3;
    float sx = 0.f, sy = 0.f, sz = 0.f;
    for (int j = tid; j < NN; j += 256) {
        sx += P[j*3]; sy += P[j*3+1]; sz += P[j*3+2];
    }
    red[0][tid] = sx; red[1][tid] = sy; red[2][tid] = sz;
    zaug[tid] = z_enc[b * DD + tid];
    __syncthreads();
    for (int s = 128; s > 0; s >>= 1) {
        if (tid < s) {
            red[0][tid] += red[0][tid + s];
            red[1][tid] += red[1][tid + s];
            red[2][tid] += red[2][tid + s];
        }
        __syncthreads();
    }
    if (tid == 0) {
        const float cx = red[0][0] / (float)NN;
        const float cy = red[1][0] / (float)NN;
        const float cz = red[2][0] / (float)NN;
        float bn0 = 0.f, bn1 = 1.f, bn2 = 0.f, bo = 0.f, bc = 0.f;
        for (int t = 0; t < TT; ++t) {
            const int bt = b * TT + t;
            const float ndv = planes[bt * 5 + 4];
            const float frac = (ndv < 1e-8f) ? -1.0f
                               : (float)counts[bt] * (1.0f / 2048.0f);
            if (frac > bc) {
                bn0 = planes[bt*5+0]; bn1 = planes[bt*5+1]; bn2 = planes[bt*5+2];
                bo = planes[bt*5+3]; bc = frac;
            }
        }
        const float sd = ((bn0 * cx + bn1 * cy) + bn2 * cz) - bo;
        zaug[DD + 0] = bn0; zaug[DD + 1] = bn1; zaug[DD + 2] = bn2; zaug[DD + 3] = sd;
        float* normals = out + (BB * DD + BB * KK * DD);
        normals[b*3+0] = bn0; normals[b*3+1] = bn1; normals[b*3+2] = bn2;
        float* offs = normals + BB * 3;
        offs[b] = bo;
        float* conf = offs + BB;
        conf[b] = bc;
    }
    __syncthreads();
    const float* wrow = Wm + (size_t)tid * (DD + 4);
    float acc = bias[tid];
    for (int j = 0; j < DD + 4; ++j) acc += zaug[j] * wrow[j];
    out[b * DD + tid] = acc;
}

extern "C" void kernel_launch(void* const* d_in, const int* in_sizes, int n_in,
                              void* d_out, int out_size, void* d_ws, size_t ws_size,
                              hipStream_t stream) {
    const float* points     = (const float*)d_in[0];
    const float* z_enc      = (const float*)d_in[1];
    const float* z_local    = (const float*)d_in[2];
    const int*   sample_idx = (const int*)d_in[4];
    const float* Wm         = (const float*)d_in[5];
    const float* bias       = (const float*)d_in[6];
    float* out = (float*)d_out;

    char* wsb = (char*)d_ws;
    int*   counts = (int*)(wsb + WS_COUNTS);
    float* planes = (float*)(wsb + WS_PLANES);
    float* gridp  = (float*)(wsb + WS_GRIDP);
    int*   head   = (int*)(wsb + WS_HEAD);
    int*   nxt    = (int*)(wsb + WS_NXT);

    // z_local passthrough
    hipMemcpyAsync(out + BB * DD, z_local,
                   (size_t)BB * KK * DD * sizeof(float),
                   hipMemcpyDeviceToDevice, stream);

    if (ws_size >= (size_t)WS_NEEDED) {
        hipMemsetAsync(head, 0xFF, (size_t)BB * NC * 4, stream);  // head = -1
        bbox_kernel<<<BB, 256, 0, stream>>>(points, gridp);
        build_kernel<<<BB, 256, 0, stream>>>(points, gridp, head, nxt);
        detect_grid_kernel<<<BB * TT, 512, 0, stream>>>(
            points, sample_idx, gridp, head, nxt, counts, planes);
    } else {
        hipMemsetAsync(counts, 0, BB * TT * sizeof(int), stream);
        detect_fallback_kernel<<<BB * TT * GG, FTHREADS, 0, stream>>>(
            points, sample_idx, counts, planes);
    }
    finalize_kernel<<<BB, 256, 0, stream>>>(points, z_enc, Wm, bias, counts, planes, out);
}

// Round 4
// 54.748 us; speedup vs baseline: 9.3587x; 1.1505x over previous
//
#include <hip/hip_runtime.h>

#define BB 8
#define NN 2048
#define TT 64
#define DD 256
#define KK 128

// ---- spatial grid ----
#define GSZ 32
#define NC (GSZ * GSZ * GSZ)
#define DTHR 0.053f     // conservative per-dim candidate radius (covers fp error)
#define D2THR 0.0025f   // sqrt(max(d2,0)) < 0.05  <=>  d2 < 0.0025 (exact)

// ---- workspace layout (bytes) ----
#define WS_COUNTS 0
#define WS_PLANES 2048
#define WS_GRIDP  12288
#define WS_HEAD   12672
#define WS_NXT    (12672 + BB * NC * 4)
#define WS_NEEDED (WS_NXT + BB * NN * 4)

// fallback (round-2 brute force) config
#define GG 2
#define FTHREADS 512

// ---------------------------------------------------------------------------
// prep: one block per batch. Phase 1: bbox reduce. Phase 2: head = -1.
// Phase 3: linked-list grid build. Points stay in registers throughout.
// ---------------------------------------------------------------------------
__global__ __launch_bounds__(256) void prep_kernel(
    const float* __restrict__ points, float* __restrict__ gridp,
    int* __restrict__ head, int* __restrict__ nxt)
{
#pragma clang fp contract(off)
    const int b = blockIdx.x, tid = threadIdx.x;
    const float* P = points + (size_t)b * NN * 3;

    // 8 points per thread in registers
    float px[8], py[8], pz[8];
    float mnx = 3.4e38f, mny = 3.4e38f, mnz = 3.4e38f;
    float mxx = -3.4e38f, mxy = -3.4e38f, mxz = -3.4e38f;
#pragma unroll
    for (int k = 0; k < 8; ++k) {
        const int j = tid + k * 256;
        px[k] = P[j * 3 + 0]; py[k] = P[j * 3 + 1]; pz[k] = P[j * 3 + 2];
        mnx = fminf(mnx, px[k]); mxx = fmaxf(mxx, px[k]);
        mny = fminf(mny, py[k]); mxy = fmaxf(mxy, py[k]);
        mnz = fminf(mnz, pz[k]); mxz = fmaxf(mxz, pz[k]);
    }

    __shared__ float smn[3][256], smx[3][256];
    __shared__ float g[9];   // org[3], h[3], inv_h[3]
    smn[0][tid] = mnx; smn[1][tid] = mny; smn[2][tid] = mnz;
    smx[0][tid] = mxx; smx[1][tid] = mxy; smx[2][tid] = mxz;
    __syncthreads();
    for (int s = 128; s > 0; s >>= 1) {
        if (tid < s)
            for (int d = 0; d < 3; ++d) {
                smn[d][tid] = fminf(smn[d][tid], smn[d][tid + s]);
                smx[d][tid] = fmaxf(smx[d][tid], smx[d][tid + s]);
            }
        __syncthreads();
    }
    if (tid == 0) {
        for (int d = 0; d < 3; ++d) {
            const float org = smn[d][0] - 1e-3f;
            const float h = fmaxf((smx[d][0] - org) * (1.0f / 31.9f), 0.06f);
            g[d] = org; g[3 + d] = h; g[6 + d] = 1.0f / h;
            float* gg = gridp + b * 12;
            gg[d] = org; gg[3 + d] = h; gg[6 + d] = 1.0f / h;
        }
    }

    // head init (this block owns head[b*NC .. b*NC+NC)
    int* headb = head + b * NC;
    for (int c = tid; c < NC; c += 256) headb[c] = -1;
    __syncthreads();

    // build
    const float ogx = g[0], ogy = g[1], ogz = g[2];
    const float ivx = g[6], ivy = g[7], ivz = g[8];
#pragma unroll
    for (int k = 0; k < 8; ++k) {
        const int j = tid + k * 256;
        int cx = (int)floorf((px[k] - ogx) * ivx);
        int cy = (int)floorf((py[k] - ogy) * ivy);
        int cz = (int)floorf((pz[k] - ogz) * ivz);
        cx = min(GSZ - 1, max(0, cx));
        cy = min(GSZ - 1, max(0, cy));
        cz = min(GSZ - 1, max(0, cz));
        const int cell = (cz * GSZ + cy) * GSZ + cx;
        nxt[b * NN + j] = atomicExch(&headb[cell], j);
    }
}

// ---------------------------------------------------------------------------
// one block per (b,t): reflect 2048 points, count grid-pruned exact matches.
// Exact d2 = (rsq + pts_sq) - dot(2r, p), non-FMA, bit-identical to reference.
// Also copies this block's slice of the z_local passthrough (frees a node).
// ---------------------------------------------------------------------------
__global__ __launch_bounds__(512) void detect_grid_kernel(
    const float* __restrict__ points, const int* __restrict__ sample_idx,
    const float* __restrict__ gridp, const int* __restrict__ head,
    const int* __restrict__ nxt, const float* __restrict__ z_local,
    int* __restrict__ counts, float* __restrict__ planes,
    float* __restrict__ out)
{
#pragma clang fp contract(off)
    __shared__ float4 spts[NN];   // {x,y,z,||p||^2}
    __shared__ int snext[NN];
    __shared__ int blk_cnt;

    const int tid = threadIdx.x;
    const int bt  = blockIdx.x;
    const int b   = bt / TT;

    // z_local passthrough slice: 65536 float4 total / 512 blocks = 128 each
    if (tid < 128) {
        const float4* zl = (const float4*)z_local;
        float4* zo = (float4*)(out + BB * DD);
        zo[bt * 128 + tid] = zl[bt * 128 + tid];
    }

    const float* P = points + (size_t)b * NN * 3;
    for (int j = tid; j < NN; j += 512) {
        float x = P[j * 3 + 0], y = P[j * 3 + 1], z = P[j * 3 + 2];
        spts[j]  = make_float4(x, y, z, (x * x + y * y) + z * z);
        snext[j] = nxt[b * NN + j];
    }
    if (tid == 0) blk_cnt = 0;

    // candidate plane (uniform across block) — exact reference ops
    const int i1 = sample_idx[bt * 2 + 0];
    const int i2 = sample_idx[bt * 2 + 1];
    const float q1x = P[i1 * 3 + 0], q1y = P[i1 * 3 + 1], q1z = P[i1 * 3 + 2];
    const float q2x = P[i2 * 3 + 0], q2y = P[i2 * 3 + 1], q2z = P[i2 * 3 + 2];
    const float dx0 = q2x - q1x, dy0 = q2y - q1y, dz0 = q2z - q1z;
    const float nd  = sqrtf((dx0 * dx0 + dy0 * dy0) + dz0 * dz0);
    const float den = nd + 1e-12f;
    const float nx = dx0 / den, ny = dy0 / den, nz = dz0 / den;
    const float e0 = (nx * (q1x + q2x)) * 0.5f;
    const float e1 = (ny * (q1y + q2y)) * 0.5f;
    const float e2 = (nz * (q1z + q2z)) * 0.5f;
    const float off = (e0 + e1) + e2;
    const float nnorm = sqrtf((nx * nx + ny * ny) + nz * nz);
    const float nden  = nnorm + 1e-12f;
    const float nnx = nx / nden, nny = ny / nden, nnz = nz / nden;

    const float* g = gridp + b * 12;
    const float ogx = g[0], ogy = g[1], ogz = g[2];
    const float hx = g[3], hy = g[4], hz = g[5];
    const float ivx = g[6], ivy = g[7], ivz = g[8];
    const int* headb = head + b * NC;

    __syncthreads();

    int cnt = 0;
    for (int q = 0; q < NN / 512; ++q) {
        const int n = tid + q * 512;
        const float4 p = spts[n];
        const float sd = ((p.x * nnx + p.y * nny) + p.z * nnz) - off;
        const float s  = 2.0f * sd;
        const float rx = p.x - s * nnx;
        const float ry = p.y - s * nny;
        const float rz = p.z - s * nnz;
        const float rsq = (rx * rx + ry * ry) + rz * rz;
        const float r2x = rx + rx, r2y = ry + ry, r2z = rz + rz; // exact *2

        // locate cell (unclamped base + per-dim +-1 range, clamp by skip)
        const float tx = rx - ogx; const float cfx = floorf(tx * ivx);
        const float ty = ry - ogy; const float cfy = floorf(ty * ivy);
        const float tz = rz - ogz; const float cfz = floorf(tz * ivz);
        const int cxi = (int)cfx, cyi = (int)cfy, czi = (int)cfz;
        const float fx = tx - cfx * hx;
        const float fy = ty - cfy * hy;
        const float fz = tz - cfz * hz;
        const int lx = (fx < DTHR) ? -1 : 0, ux = (fx > hx - DTHR) ? 1 : 0;
        const int ly = (fy < DTHR) ? -1 : 0, uy = (fy > hy - DTHR) ? 1 : 0;
        const int lz = (fz < DTHR) ? -1 : 0, uz = (fz > hz - DTHR) ? 1 : 0;

        int matched = 0;
        for (int dz = lz; dz <= uz; ++dz) {
            const int cz = czi + dz; if ((unsigned)cz >= GSZ) continue;
            for (int dy = ly; dy <= uy; ++dy) {
                const int cy = cyi + dy; if ((unsigned)cy >= GSZ) continue;
                for (int dxi = lx; dxi <= ux; ++dxi) {
                    const int cx = cxi + dxi; if ((unsigned)cx >= GSZ) continue;
                    int j = headb[(cz * GSZ + cy) * GSZ + cx];
                    while (j >= 0) {
                        const float4 pm = spts[j];
                        const float c2 = (r2x * pm.x + r2y * pm.y) + r2z * pm.z;
                        const float t1 = rsq + pm.w;
                        matched |= ((t1 - c2) < D2THR) ? 1 : 0;
                        j = snext[j];
                    }
                }
            }
        }
        cnt += matched;
    }

    for (int o = 32; o > 0; o >>= 1) cnt += __shfl_down(cnt, o);
    if ((tid & 63) == 0) atomicAdd(&blk_cnt, cnt);
    __syncthreads();

    if (tid == 0) {
        counts[bt] = blk_cnt;
        planes[bt * 5 + 0] = nx;
        planes[bt * 5 + 1] = ny;
        planes[bt * 5 + 2] = nz;
        planes[bt * 5 + 3] = off;
        planes[bt * 5 + 4] = nd;
    }
}

// ---------------------------------------------------------------------------
// Fallback brute-force detect (round-2 kernel) if ws_size is too small.
// ---------------------------------------------------------------------------
__global__ __launch_bounds__(FTHREADS) void detect_fallback_kernel(
    const float* __restrict__ points, const int* __restrict__ sample_idx,
    int* __restrict__ counts, float* __restrict__ planes)
{
#pragma clang fp contract(off)
    __shared__ float4 spts[NN];
    const int tid = threadIdx.x;
    const int blk = blockIdx.x;
    const int bt = blk / GG, chunk = blk % GG, b = bt / TT;
    const float* P = points + (size_t)b * NN * 3;
    for (int j = tid; j < NN; j += FTHREADS) {
        float x = P[j*3], y = P[j*3+1], z = P[j*3+2];
        spts[j] = make_float4(x, y, z, (x*x + y*y) + z*z);
    }
    const int i1 = sample_idx[bt * 2 + 0];
    const int i2 = sample_idx[bt * 2 + 1];
    const float q1x = P[i1*3], q1y = P[i1*3+1], q1z = P[i1*3+2];
    const float q2x = P[i2*3], q2y = P[i2*3+1], q2z = P[i2*3+2];
    const float dx = q2x - q1x, dy = q2y - q1y, dz = q2z - q1z;
    const float nd  = sqrtf((dx*dx + dy*dy) + dz*dz);
    const float den = nd + 1e-12f;
    const float nx = dx/den, ny = dy/den, nz = dz/den;
    const float e0 = (nx*(q1x+q2x))*0.5f, e1 = (ny*(q1y+q2y))*0.5f, e2 = (nz*(q1z+q2z))*0.5f;
    const float off = (e0 + e1) + e2;
    const float nnorm = sqrtf((nx*nx + ny*ny) + nz*nz);
    const float nden = nnorm + 1e-12f;
    const float nnx = nx/nden, nny = ny/nden, nnz = nz/nden;
    __syncthreads();
    const int n0 = chunk * (NN / GG) + tid;
    const int n1 = n0 + FTHREADS;
    float r2x0, r2y0, r2z0, rsq0, r2x1, r2y1, r2z1, rsq1;
    {
        const float4 p0 = spts[n0];
        const float sd = ((p0.x*nnx + p0.y*nny) + p0.z*nnz) - off;
        const float s = 2.0f*sd;
        const float rx = p0.x - s*nnx, ry = p0.y - s*nny, rz = p0.z - s*nnz;
        rsq0 = (rx*rx + ry*ry) + rz*rz;
        r2x0 = rx+rx; r2y0 = ry+ry; r2z0 = rz+rz;
    }
    {
        const float4 p1 = spts[n1];
        const float sd = ((p1.x*nnx + p1.y*nny) + p1.z*nnz) - off;
        const float s = 2.0f*sd;
        const float rx = p1.x - s*nnx, ry = p1.y - s*nny, rz = p1.z - s*nnz;
        rsq1 = (rx*rx + ry*ry) + rz*rz;
        r2x1 = rx+rx; r2y1 = ry+ry; r2z1 = rz+rz;
    }
    float md0 = 3.4e38f, md1 = 3.4e38f;
    float4 p = spts[0];
#pragma unroll 8
    for (int m = 0; m < NN - 1; ++m) {
        const float4 pn = spts[m + 1];
        const float c0 = (r2x0*p.x + r2y0*p.y) + r2z0*p.z;
        md0 = fminf(md0, (rsq0 + p.w) - c0);
        const float c1 = (r2x1*p.x + r2y1*p.y) + r2z1*p.z;
        md1 = fminf(md1, (rsq1 + p.w) - c1);
        p = pn;
    }
    {
        const float c0 = (r2x0*p.x + r2y0*p.y) + r2z0*p.z;
        md0 = fminf(md0, (rsq0 + p.w) - c0);
        const float c1 = (r2x1*p.x + r2y1*p.y) + r2z1*p.z;
        md1 = fminf(md1, (rsq1 + p.w) - c1);
    }
    const unsigned long long b0 = __ballot(md0 < D2THR);
    const unsigned long long b1 = __ballot(md1 < D2THR);
    if ((tid & 63) == 0) atomicAdd(&counts[bt], __popcll(b0) + __popcll(b1));
    if (tid == 0 && chunk == 0) {
        planes[bt*5+0] = nx; planes[bt*5+1] = ny; planes[bt*5+2] = nz;
        planes[bt*5+3] = off; planes[bt*5+4] = nd;
    }
}

// ---------------------------------------------------------------------------
// Kernel: per-batch argmax (first-wins), centroid, GEMV, small outputs.
// ---------------------------------------------------------------------------
__global__ __launch_bounds__(256) void finalize_kernel(
    const float* __restrict__ points, const float* __restrict__ z_enc,
    const float* __restrict__ Wm, const float* __restrict__ bias,
    const int* __restrict__ counts, const float* __restrict__ planes,
    float* __restrict__ out)
{
    const int b = blockIdx.x, tid = threadIdx.x;
    __shared__ float zaug[DD + 4];
    __shared__ float red[3][256];

    const float* P = points + (size_t)b * NN * 3;
    float sx = 0.f, sy = 0.f, sz = 0.f;
    for (int j = tid; j < NN; j += 256) {
        sx += P[j*3]; sy += P[j*3+1]; sz += P[j*3+2];
    }
    red[0][tid] = sx; red[1][tid] = sy; red[2][tid] = sz;
    zaug[tid] = z_enc[b * DD + tid];
    __syncthreads();
    for (int s = 128; s > 0; s >>= 1) {
        if (tid < s) {
            red[0][tid] += red[0][tid + s];
            red[1][tid] += red[1][tid + s];
            red[2][tid] += red[2][tid + s];
        }
        __syncthreads();
    }
    if (tid == 0) {
        const float cx = red[0][0] / (float)NN;
        const float cy = red[1][0] / (float)NN;
        const float cz = red[2][0] / (float)NN;
        float bn0 = 0.f, bn1 = 1.f, bn2 = 0.f, bo = 0.f, bc = 0.f;
        for (int t = 0; t < TT; ++t) {
            const int bt = b * TT + t;
            const float ndv = planes[bt * 5 + 4];
            const float frac = (ndv < 1e-8f) ? -1.0f
                               : (float)counts[bt] * (1.0f / 2048.0f);
            if (frac > bc) {
                bn0 = planes[bt*5+0]; bn1 = planes[bt*5+1]; bn2 = planes[bt*5+2];
                bo = planes[bt*5+3]; bc = frac;
            }
        }
        const float sd = ((bn0 * cx + bn1 * cy) + bn2 * cz) - bo;
        zaug[DD + 0] = bn0; zaug[DD + 1] = bn1; zaug[DD + 2] = bn2; zaug[DD + 3] = sd;
        float* normals = out + (BB * DD + BB * KK * DD);
        normals[b*3+0] = bn0; normals[b*3+1] = bn1; normals[b*3+2] = bn2;
        float* offs = normals + BB * 3;
        offs[b] = bo;
        float* conf = offs + BB;
        conf[b] = bc;
    }
    __syncthreads();
    const float* wrow = Wm + (size_t)tid * (DD + 4);
    float acc = bias[tid];
    for (int j = 0; j < DD + 4; ++j) acc += zaug[j] * wrow[j];
    out[b * DD + tid] = acc;
}

extern "C" void kernel_launch(void* const* d_in, const int* in_sizes, int n_in,
                              void* d_out, int out_size, void* d_ws, size_t ws_size,
                              hipStream_t stream) {
    const float* points     = (const float*)d_in[0];
    const float* z_enc      = (const float*)d_in[1];
    const float* z_local    = (const float*)d_in[2];
    const int*   sample_idx = (const int*)d_in[4];
    const float* Wm         = (const float*)d_in[5];
    const float* bias       = (const float*)d_in[6];
    float* out = (float*)d_out;

    char* wsb = (char*)d_ws;
    int*   counts = (int*)(wsb + WS_COUNTS);
    float* planes = (float*)(wsb + WS_PLANES);
    float* gridp  = (float*)(wsb + WS_GRIDP);
    int*   head   = (int*)(wsb + WS_HEAD);
    int*   nxt    = (int*)(wsb + WS_NXT);

    if (ws_size >= (size_t)WS_NEEDED) {
        prep_kernel<<<BB, 256, 0, stream>>>(points, gridp, head, nxt);
        detect_grid_kernel<<<BB * TT, 512, 0, stream>>>(
            points, sample_idx, gridp, head, nxt, z_local, counts, planes, out);
    } else {
        hipMemcpyAsync(out + BB * DD, z_local,
                       (size_t)BB * KK * DD * sizeof(float),
                       hipMemcpyDeviceToDevice, stream);
        hipMemsetAsync(counts, 0, BB * TT * sizeof(int), stream);
        detect_fallback_kernel<<<BB * TT * GG, FTHREADS, 0, stream>>>(
            points, sample_idx, counts, planes);
    }
    finalize_kernel<<<BB, 256, 0, stream>>>(points, z_enc, Wm, bias, counts, planes, out);
}